// Round 3
// baseline (954.991 us; speedup 1.0000x reference)
//
#include <hip/hip_runtime.h>

#define T_TOK 4096
#define H_DIM 2048
#define I_DIM 1408
#define E_NUM 8
#define NI2   (2 * I_DIM)   // 2816

typedef int v4i __attribute__((ext_vector_type(4)));

#define GLD_LDS16(gptr, lptr)                                                        \
  __builtin_amdgcn_global_load_lds(                                                  \
      (const __attribute__((address_space(1))) void*)(gptr),                         \
      (__attribute__((address_space(3))) void*)(lptr), 16, 0, 0)

// ---------------------------------------------------------------------------
// Pack int32 -> int8
// ---------------------------------------------------------------------------
__global__ __launch_bounds__(256) void pack_i8(const int* __restrict__ src,
                                               signed char* __restrict__ dst,
                                               int n16) {
  int i = blockIdx.x * 256 + threadIdx.x;
  if (i >= n16) return;
  const int4* s4 = (const int4*)src + (size_t)i * 4;
  int4 v0 = s4[0], v1 = s4[1], v2 = s4[2], v3 = s4[3];
  union { signed char c[16]; int4 v; } pk;
  pk.c[0] = (signed char)v0.x;  pk.c[1] = (signed char)v0.y;
  pk.c[2] = (signed char)v0.z;  pk.c[3] = (signed char)v0.w;
  pk.c[4] = (signed char)v1.x;  pk.c[5] = (signed char)v1.y;
  pk.c[6] = (signed char)v1.z;  pk.c[7] = (signed char)v1.w;
  pk.c[8] = (signed char)v2.x;  pk.c[9] = (signed char)v2.y;
  pk.c[10] = (signed char)v2.z; pk.c[11] = (signed char)v2.w;
  pk.c[12] = (signed char)v3.x; pk.c[13] = (signed char)v3.y;
  pk.c[14] = (signed char)v3.z; pk.c[15] = (signed char)v3.w;
  ((int4*)dst)[i] = pk.v;
}

// ---------------------------------------------------------------------------
// Gate logits + top-2 routing + dynamic int8 quant of hidden_states.
// ---------------------------------------------------------------------------
__global__ __launch_bounds__(256) void gate_route_quant(
    const float* __restrict__ hs, const float* __restrict__ gw,
    signed char* __restrict__ qin, float* __restrict__ s_in,
    int* __restrict__ tok_list, int* __restrict__ cnt,
    int* __restrict__ epos, float* __restrict__ gts) {
  const int t = blockIdx.x;
  const int tid = threadIdx.x;
  const int lane = tid & 63;
  const int wave = tid >> 6;
  const float* row = hs + (size_t)t * H_DIM;

  const float4* r4 = (const float4*)row + tid * 2;
  float4 xa = r4[0], xb = r4[1];
  float x[8] = {xa.x, xa.y, xa.z, xa.w, xb.x, xb.y, xb.z, xb.w};

  double pd[8];
  for (int e = 0; e < 8; e++) pd[e] = 0.0;
  float am = 0.f;
  for (int j = 0; j < 8; j++) {
    float v = x[j];
    am = fmaxf(am, fabsf(v));
    int col = tid * 8 + j;
    for (int e = 0; e < 8; e++)
      pd[e] += (double)v * (double)gw[e * H_DIM + col];
  }
  for (int e = 0; e < 8; e++)
    for (int s = 32; s; s >>= 1) pd[e] += __shfl_down(pd[e], s);
  for (int s = 32; s; s >>= 1) am = fmaxf(am, __shfl_down(am, s));

  __shared__ double sred[4][8];
  __shared__ float sam[4];
  __shared__ float sbc;
  if (lane == 0) {
    for (int e = 0; e < 8; e++) sred[wave][e] = pd[e];
    sam[wave] = am;
  }
  __syncthreads();
  if (tid == 0) {
    float l[8];
    for (int e = 0; e < 8; e++)
      l[e] = (float)(sred[0][e] + sred[1][e] + sred[2][e] + sred[3][e]);
    float amx = fmaxf(fmaxf(sam[0], sam[1]), fmaxf(sam[2], sam[3]));
    float s = fmaxf(amx / 127.0f, 1e-8f);
    s_in[t] = s;
    sbc = s;
    int i1 = 0;
    for (int e = 1; e < 8; e++) if (l[e] > l[i1]) i1 = e;
    int i2 = -1;
    for (int e = 0; e < 8; e++) {
      if (e == i1) continue;
      if (i2 < 0 || l[e] > l[i2]) i2 = e;
    }
    float d = expf(l[i2] - l[i1]);
    float g1 = 1.0f / (1.0f + d);
    float g2 = d / (1.0f + d);
    int p1 = atomicAdd(&cnt[i1], 1);
    tok_list[i1 * T_TOK + p1] = t;
    int p2 = atomicAdd(&cnt[i2], 1);
    tok_list[i2 * T_TOK + p2] = t;
    epos[2 * t] = (i1 << 16) | p1;     gts[2 * t] = g1;
    epos[2 * t + 1] = (i2 << 16) | p2; gts[2 * t + 1] = g2;
  }
  __syncthreads();
  float s = sbc;
  union { signed char c[8]; unsigned long long u; } pk;
  for (int j = 0; j < 8; j++) {
    float q = rintf(x[j] / s);
    q = fminf(127.f, fmaxf(-127.f, q));
    pk.c[j] = (signed char)q;
  }
  ((unsigned long long*)(qin + (size_t)t * H_DIM))[tid] = pk.u;
}

__global__ void calc_off(const int* __restrict__ cnt, int* __restrict__ off) {
  if (threadIdx.x == 0) {
    int s = 0;
    for (int e = 0; e < E_NUM; e++) { off[e] = s; s += cnt[e]; }
  }
}

// ---------------------------------------------------------------------------
// GEMM1: double-buffered LDS pipeline + XCD-aware block swizzle.
// grid.x = 8(xcd) * 4(mhi) * 11(n) * 8(e) = 2816
// ---------------------------------------------------------------------------
__global__ __launch_bounds__(256, 2) void gemm1_silu(
    const signed char* __restrict__ qw13, const signed char* __restrict__ qin,
    const float* __restrict__ s_in, const float* __restrict__ s13,
    const int* __restrict__ tok_list, const int* __restrict__ cnt,
    const int* __restrict__ off, float* __restrict__ act,
    unsigned int* __restrict__ amax) {
  const int id = blockIdx.x;
  const int xcd = id & 7;
  const int q = id >> 3;           // [0, 352)
  const int mhi = q & 3;
  const int nq = (q >> 2) % 11;
  const int e = (q >> 2) / 11;
  const int mb = xcd + 8 * mhi;    // 0..31

  const int ce = cnt[e];
  const int m0 = mb * 128;
  if (m0 >= ce) return;
  const int n0 = nq * 128;

  __shared__ __align__(16) signed char As[2][128 * 64];
  __shared__ __align__(16) signed char Bg[2][128 * 64];
  __shared__ __align__(16) signed char Bu[2][128 * 64];

  const int tid = threadIdx.x;
  const int lane = tid & 63;
  const int wave = tid >> 6;
  const int quad = lane >> 4;
  const int ln = lane & 15;
  const int wm = wave & 1;
  const int wn = wave >> 1;

  const int* tl = tok_list + e * T_TOK;
  const int rowA0 = tid >> 2;            // 0..63
  const int rowA1 = rowA0 + 64;          // 64..127
  const int kc = ((tid ^ (tid >> 4)) & 3) * 16;

  const int tA0 = tl[min(m0 + rowA0, ce - 1)];
  const int tA1 = tl[min(m0 + rowA1, ce - 1)];
  const signed char* gA0 = qin + (size_t)tA0 * H_DIM + kc;
  const signed char* gA1 = qin + (size_t)tA1 * H_DIM + kc;
  const signed char* w13e = qw13 + (size_t)e * NI2 * H_DIM;
  const signed char* gBg0 = w13e + (size_t)(n0 + rowA0) * H_DIM + kc;
  const signed char* gBg1 = w13e + (size_t)(n0 + rowA1) * H_DIM + kc;
  const signed char* gBu0 = gBg0 + (size_t)I_DIM * H_DIM;
  const signed char* gBu1 = gBg1 + (size_t)I_DIM * H_DIM;
  const int lds0 = (tid & ~63) * 16;
  const int lds1 = 4096 + lds0;
  const int rq0 = ((quad ^ (ln >> 2)) & 3) * 16;

  auto stage = [&](int k0, int b) {
    GLD_LDS16(gA0 + k0, As[b] + lds0);
    GLD_LDS16(gA1 + k0, As[b] + lds1);
    GLD_LDS16(gBg0 + k0, Bg[b] + lds0);
    GLD_LDS16(gBg1 + k0, Bg[b] + lds1);
    GLD_LDS16(gBu0 + k0, Bu[b] + lds0);
    GLD_LDS16(gBu1 + k0, Bu[b] + lds1);
  };

  v4i accg[4][4], accu[4][4];
  v4i zero = {0, 0, 0, 0};
#pragma unroll
  for (int i = 0; i < 4; i++)
#pragma unroll
    for (int j = 0; j < 4; j++) { accg[i][j] = zero; accu[i][j] = zero; }

  const int NK = H_DIM / 64;
  stage(0, 0);
  for (int ki = 0; ki < NK; ki++) {
    __syncthreads();                       // drains this wave's stage(ki) loads
    if (ki + 1 < NK) stage((ki + 1) * 64, (ki + 1) & 1);  // in flight over compute
    const int b = ki & 1;

    v4i af[4], bgf[4], buf_[4];
#pragma unroll
    for (int mt = 0; mt < 4; mt++)
      af[mt] = *(const v4i*)(As[b] + (wm * 64 + mt * 16 + ln) * 64 + rq0);
#pragma unroll
    for (int nt = 0; nt < 4; nt++) {
      bgf[nt] = *(const v4i*)(Bg[b] + (wn * 64 + nt * 16 + ln) * 64 + rq0);
      buf_[nt] = *(const v4i*)(Bu[b] + (wn * 64 + nt * 16 + ln) * 64 + rq0);
    }
#pragma unroll
    for (int mt = 0; mt < 4; mt++)
#pragma unroll
      for (int nt = 0; nt < 4; nt++) {
        accg[mt][nt] = __builtin_amdgcn_mfma_i32_16x16x64_i8(af[mt], bgf[nt], accg[mt][nt], 0, 0, 0);
        accu[mt][nt] = __builtin_amdgcn_mfma_i32_16x16x64_i8(af[mt], buf_[nt], accu[mt][nt], 0, 0, 0);
      }
  }

  const float* s13e = s13 + e * NI2;
  float sg[4], su[4];
  int ncol[4];
#pragma unroll
  for (int nt = 0; nt < 4; nt++) {
    int n = n0 + wn * 64 + nt * 16 + ln;
    ncol[nt] = n;
    sg[nt] = s13e[n];
    su[nt] = s13e[I_DIM + n];
  }
  const int offe = off[e];
#pragma unroll
  for (int mt = 0; mt < 4; mt++) {
#pragma unroll
    for (int r = 0; r < 4; r++) {
      int mrel = m0 + wm * 64 + mt * 16 + quad * 4 + r;
      bool valid = mrel < ce;
      int tok = tl[valid ? mrel : 0];
      float si = s_in[tok];
      int crow = offe + mrel;
      float* arow = act + (size_t)crow * I_DIM;
      float am = 0.f;
#pragma unroll
      for (int nt = 0; nt < 4; nt++) {
        float g = (float)accg[mt][nt][r] * si * sg[nt];
        float u = (float)accu[mt][nt][r] * si * su[nt];
        float a = g / (1.0f + expf(-g)) * u;
        if (valid) arow[ncol[nt]] = a;
        am = fmaxf(am, fabsf(a));
      }
      for (int s = 1; s < 16; s <<= 1) am = fmaxf(am, __shfl_xor(am, s, 16));
      if (valid && ln == 0) atomicMax(amax + crow, __float_as_uint(am));
    }
  }
}

// ---------------------------------------------------------------------------
// Per-row dynamic int8 quant of act
// ---------------------------------------------------------------------------
__global__ __launch_bounds__(256) void quant_act(const float* __restrict__ act,
                                                 const unsigned int* __restrict__ amax,
                                                 signed char* __restrict__ qa,
                                                 float* __restrict__ s_a) {
  const int r = blockIdx.x;
  float am = __uint_as_float(amax[r]);
  float s = fmaxf(am / 127.0f, 1e-8f);
  if (threadIdx.x == 0) s_a[r] = s;
  const float* arow = act + (size_t)r * I_DIM;
  signed char* qrow = qa + (size_t)r * I_DIM;
  for (int j = threadIdx.x; j < I_DIM; j += 256) {
    float q = rintf(arow[j] / s);
    q = fminf(127.f, fmaxf(-127.f, q));
    qrow[j] = (signed char)q;
  }
}

// ---------------------------------------------------------------------------
// GEMM2: double-buffered pipeline + swizzle. grid.x = 8*4*16*8 = 4096
// ---------------------------------------------------------------------------
__global__ __launch_bounds__(256, 2) void gemm2_h2(
    const signed char* __restrict__ qw2, const signed char* __restrict__ qa,
    const float* __restrict__ s_a, const float* __restrict__ s2w,
    const int* __restrict__ cnt, const int* __restrict__ off,
    float* __restrict__ h2s) {
  const int id = blockIdx.x;
  const int xcd = id & 7;
  const int q = id >> 3;            // [0, 512)
  const int mhi = q & 3;
  const int nq = (q >> 2) & 15;
  const int e = (q >> 2) >> 4;
  const int mb = xcd + 8 * mhi;

  const int ce = cnt[e];
  const int m0 = mb * 128;
  if (m0 >= ce) return;
  const int n0 = nq * 128;
  const int offe = off[e];

  __shared__ __align__(16) signed char As[2][128 * 64];
  __shared__ __align__(16) signed char Bs[2][128 * 64];

  const int tid = threadIdx.x;
  const int lane = tid & 63;
  const int wave = tid >> 6;
  const int quad = lane >> 4;
  const int ln = lane & 15;
  const int wm = wave & 1;
  const int wn = wave >> 1;

  const int rowA0 = tid >> 2;
  const int rowA1 = rowA0 + 64;
  const int kc = ((tid ^ (tid >> 4)) & 3) * 16;

  const signed char* gA0 = qa + (size_t)(offe + min(m0 + rowA0, ce - 1)) * I_DIM + kc;
  const signed char* gA1 = qa + (size_t)(offe + min(m0 + rowA1, ce - 1)) * I_DIM + kc;
  const signed char* w2e = qw2 + (size_t)e * H_DIM * I_DIM;
  const signed char* gB0 = w2e + (size_t)(n0 + rowA0) * I_DIM + kc;
  const signed char* gB1 = w2e + (size_t)(n0 + rowA1) * I_DIM + kc;
  const int lds0 = (tid & ~63) * 16;
  const int lds1 = 4096 + lds0;
  const int rq0 = ((quad ^ (ln >> 2)) & 3) * 16;

  auto stage = [&](int k0, int b) {
    GLD_LDS16(gA0 + k0, As[b] + lds0);
    GLD_LDS16(gA1 + k0, As[b] + lds1);
    GLD_LDS16(gB0 + k0, Bs[b] + lds0);
    GLD_LDS16(gB1 + k0, Bs[b] + lds1);
  };

  v4i acc[4][4];
  v4i zero = {0, 0, 0, 0};
#pragma unroll
  for (int i = 0; i < 4; i++)
#pragma unroll
    for (int j = 0; j < 4; j++) acc[i][j] = zero;

  const int NK = I_DIM / 64;
  stage(0, 0);
  for (int ki = 0; ki < NK; ki++) {
    __syncthreads();
    if (ki + 1 < NK) stage((ki + 1) * 64, (ki + 1) & 1);
    const int b = ki & 1;

    v4i af[4], bf[4];
#pragma unroll
    for (int mt = 0; mt < 4; mt++)
      af[mt] = *(const v4i*)(As[b] + (wm * 64 + mt * 16 + ln) * 64 + rq0);
#pragma unroll
    for (int nt = 0; nt < 4; nt++)
      bf[nt] = *(const v4i*)(Bs[b] + (wn * 64 + nt * 16 + ln) * 64 + rq0);
#pragma unroll
    for (int mt = 0; mt < 4; mt++)
#pragma unroll
      for (int nt = 0; nt < 4; nt++)
        acc[mt][nt] = __builtin_amdgcn_mfma_i32_16x16x64_i8(af[mt], bf[nt], acc[mt][nt], 0, 0, 0);
  }

  const float* s2e = s2w + e * H_DIM;
  float sw[4];
  int ncol[4];
#pragma unroll
  for (int nt = 0; nt < 4; nt++) {
    int n = n0 + wn * 64 + nt * 16 + ln;
    ncol[nt] = n;
    sw[nt] = s2e[n];
  }
#pragma unroll
  for (int mt = 0; mt < 4; mt++) {
#pragma unroll
    for (int r = 0; r < 4; r++) {
      int mrel = m0 + wm * 64 + mt * 16 + quad * 4 + r;
      if (mrel >= ce) continue;
      float sa = s_a[offe + mrel];
      float* orow = h2s + (size_t)(offe + mrel) * H_DIM;
#pragma unroll
      for (int nt = 0; nt < 4; nt++)
        orow[ncol[nt]] = (float)acc[mt][nt][r] * sa * sw[nt];
    }
  }
}

// ---------------------------------------------------------------------------
// Final gather: out[t] = g1 * h2s[r1] + g2 * h2s[r2]
// ---------------------------------------------------------------------------
__global__ __launch_bounds__(256) void gather_out(
    const float* __restrict__ h2s, const int* __restrict__ epos,
    const float* __restrict__ gts, const int* __restrict__ off,
    float* __restrict__ out) {
  const int t = blockIdx.x;
  int a = epos[2 * t], b = epos[2 * t + 1];
  float g1 = gts[2 * t], g2 = gts[2 * t + 1];
  int r1 = off[a >> 16] + (a & 0xffff);
  int r2 = off[b >> 16] + (b & 0xffff);
  const float4* R1 = (const float4*)(h2s + (size_t)r1 * H_DIM);
  const float4* R2 = (const float4*)(h2s + (size_t)r2 * H_DIM);
  float4* O = (float4*)(out + (size_t)t * H_DIM);
  for (int c = threadIdx.x; c < H_DIM / 4; c += 256) {
    float4 x = R1[c], y = R2[c];
    float4 z;
    z.x = g1 * x.x + g2 * y.x;
    z.y = g1 * x.y + g2 * y.y;
    z.z = g1 * x.z + g2 * y.z;
    z.w = g1 * x.w + g2 * y.w;
    O[c] = z;
  }
}

// ---------------------------------------------------------------------------
extern "C" void kernel_launch(void* const* d_in, const int* in_sizes, int n_in,
                              void* d_out, int out_size, void* d_ws, size_t ws_size,
                              hipStream_t stream) {
  const float* hs = (const float*)d_in[0];
  const float* gw = (const float*)d_in[1];
  const int* w13 = (const int*)d_in[2];
  const float* s13 = (const float*)d_in[3];
  const int* w2 = (const int*)d_in[4];
  const float* s2w = (const float*)d_in[5];
  float* out = (float*)d_out;

  char* ws = (char*)d_ws;
  size_t o = 0;
  auto take = [&](size_t b) {
    char* p = ws + o;
    o += (b + 255) & ~(size_t)255;
    return p;
  };
  signed char* qw13 = (signed char*)take((size_t)E_NUM * NI2 * H_DIM);       // 46.1 MB
  signed char* qin = (signed char*)take((size_t)T_TOK * H_DIM);              // 8.4 MB
  float* act = (float*)take((size_t)T_TOK * 2 * I_DIM * 4);                  // 46.1 MB
  float* h2s = (float*)qw13;  // aliases dead qw13+qin+act space (67.1 MB needed)
  signed char* qw2 = (signed char*)take((size_t)E_NUM * H_DIM * I_DIM);      // 23.1 MB
  signed char* qa = (signed char*)take((size_t)T_TOK * 2 * I_DIM);           // 11.5 MB
  float* sin_ = (float*)take((size_t)T_TOK * 4);
  float* sa = (float*)take((size_t)T_TOK * 2 * 4);
  unsigned int* amax = (unsigned int*)take((size_t)T_TOK * 2 * 4);
  int* tokl = (int*)take((size_t)E_NUM * T_TOK * 4);
  int* epos = (int*)take((size_t)T_TOK * 2 * 4);
  float* gts = (float*)take((size_t)T_TOK * 2 * 4);
  int* cnt = (int*)take(E_NUM * 4);
  int* off = (int*)take(E_NUM * 4);

  hipMemsetAsync(cnt, 0, E_NUM * 4, stream);
  hipMemsetAsync(amax, 0, (size_t)T_TOK * 2 * 4, stream);

  {
    int n16 = E_NUM * NI2 * H_DIM / 16;
    pack_i8<<<(n16 + 255) / 256, 256, 0, stream>>>(w13, qw13, n16);
  }
  {
    int n16 = E_NUM * H_DIM * I_DIM / 16;
    pack_i8<<<(n16 + 255) / 256, 256, 0, stream>>>(w2, qw2, n16);
  }
  gate_route_quant<<<T_TOK, 256, 0, stream>>>(hs, gw, qin, sin_, tokl, cnt, epos, gts);
  calc_off<<<1, 64, 0, stream>>>(cnt, off);
  gemm1_silu<<<8 * 4 * 11 * 8, 256, 0, stream>>>(qw13, qin, sin_, s13, tokl, cnt, off, act, amax);
  quant_act<<<T_TOK * 2, 256, 0, stream>>>(act, amax, qa, sa);
  gemm2_h2<<<8 * 4 * 16 * 8, 256, 0, stream>>>(qw2, qa, sa, s2w, cnt, off, h2s);
  gather_out<<<T_TOK, 256, 0, stream>>>(h2s, epos, gts, off, out);
}

// Round 4
// 584.116 us; speedup vs baseline: 1.6349x; 1.6349x over previous
//
#include <hip/hip_runtime.h>

#define T_TOK 4096
#define H_DIM 2048
#define I_DIM 1408
#define E_NUM 8
#define NI2   (2 * I_DIM)   // 2816

typedef int v4i __attribute__((ext_vector_type(4)));

#define GLD_LDS16(gptr, lptr)                                                        \
  __builtin_amdgcn_global_load_lds(                                                  \
      (const __attribute__((address_space(1))) void*)(gptr),                         \
      (__attribute__((address_space(3))) void*)(lptr), 16, 0, 0)

// ---------------------------------------------------------------------------
// Pack int32 -> int8 for both weight tensors in one launch
// ---------------------------------------------------------------------------
__global__ __launch_bounds__(256) void pack_all(const int* __restrict__ w13,
                                                const int* __restrict__ w2,
                                                signed char* __restrict__ qw13,
                                                signed char* __restrict__ qw2,
                                                int n16a, int n16tot) {
  int i = blockIdx.x * 256 + threadIdx.x;
  if (i >= n16tot) return;
  const int* src;
  signed char* dst;
  int j;
  if (i < n16a) { src = w13; dst = qw13; j = i; }
  else          { src = w2;  dst = qw2;  j = i - n16a; }
  const int4* s4 = (const int4*)src + (size_t)j * 4;
  int4 v0 = s4[0], v1 = s4[1], v2 = s4[2], v3 = s4[3];
  union { signed char c[16]; int4 v; } pk;
  pk.c[0] = (signed char)v0.x;  pk.c[1] = (signed char)v0.y;
  pk.c[2] = (signed char)v0.z;  pk.c[3] = (signed char)v0.w;
  pk.c[4] = (signed char)v1.x;  pk.c[5] = (signed char)v1.y;
  pk.c[6] = (signed char)v1.z;  pk.c[7] = (signed char)v1.w;
  pk.c[8] = (signed char)v2.x;  pk.c[9] = (signed char)v2.y;
  pk.c[10] = (signed char)v2.z; pk.c[11] = (signed char)v2.w;
  pk.c[12] = (signed char)v3.x; pk.c[13] = (signed char)v3.y;
  pk.c[14] = (signed char)v3.z; pk.c[15] = (signed char)v3.w;
  ((int4*)dst)[j] = pk.v;
}

// ---------------------------------------------------------------------------
// Gate logits + top-2 + dynamic int8 quant. No atomics: writes top-2 ids/gates.
// ---------------------------------------------------------------------------
__global__ __launch_bounds__(256) void gate_route_quant(
    const float* __restrict__ hs, const float* __restrict__ gw,
    signed char* __restrict__ qin, float* __restrict__ s_in,
    int* __restrict__ tope, float* __restrict__ gts) {
  const int t = blockIdx.x;
  const int tid = threadIdx.x;
  const int lane = tid & 63;
  const int wave = tid >> 6;
  const float* row = hs + (size_t)t * H_DIM;

  const float4* r4 = (const float4*)row + tid * 2;
  float4 xa = r4[0], xb = r4[1];
  float x[8] = {xa.x, xa.y, xa.z, xa.w, xb.x, xb.y, xb.z, xb.w};

  double pd[8];
  for (int e = 0; e < 8; e++) pd[e] = 0.0;
  float am = 0.f;
  for (int j = 0; j < 8; j++) {
    float v = x[j];
    am = fmaxf(am, fabsf(v));
    int col = tid * 8 + j;
    for (int e = 0; e < 8; e++)
      pd[e] += (double)v * (double)gw[e * H_DIM + col];
  }
  for (int e = 0; e < 8; e++)
    for (int s = 32; s; s >>= 1) pd[e] += __shfl_down(pd[e], s);
  for (int s = 32; s; s >>= 1) am = fmaxf(am, __shfl_down(am, s));

  __shared__ double sred[4][8];
  __shared__ float sam[4];
  __shared__ float sbc;
  if (lane == 0) {
    for (int e = 0; e < 8; e++) sred[wave][e] = pd[e];
    sam[wave] = am;
  }
  __syncthreads();
  if (tid == 0) {
    float l[8];
    for (int e = 0; e < 8; e++)
      l[e] = (float)(sred[0][e] + sred[1][e] + sred[2][e] + sred[3][e]);
    float amx = fmaxf(fmaxf(sam[0], sam[1]), fmaxf(sam[2], sam[3]));
    float s = fmaxf(amx / 127.0f, 1e-8f);
    s_in[t] = s;
    sbc = s;
    int i1 = 0;
    for (int e = 1; e < 8; e++) if (l[e] > l[i1]) i1 = e;
    int i2 = -1;
    for (int e = 0; e < 8; e++) {
      if (e == i1) continue;
      if (i2 < 0 || l[e] > l[i2]) i2 = e;
    }
    float d = expf(l[i2] - l[i1]);
    tope[2 * t] = i1;     gts[2 * t] = 1.0f / (1.0f + d);
    tope[2 * t + 1] = i2; gts[2 * t + 1] = d / (1.0f + d);
  }
  __syncthreads();
  float s = sbc;
  union { signed char c[8]; unsigned long long u; } pk;
  for (int j = 0; j < 8; j++) {
    float q = rintf(x[j] / s);
    q = fminf(127.f, fmaxf(-127.f, q));
    pk.c[j] = (signed char)q;
  }
  ((unsigned long long*)(qin + (size_t)t * H_DIM))[tid] = pk.u;
}

// ---------------------------------------------------------------------------
// Build per-expert token lists deterministically (ballot prefix, no atomics).
// One block per expert.
// ---------------------------------------------------------------------------
__global__ __launch_bounds__(256) void build_lists(
    const int* __restrict__ tope, int* __restrict__ tok_list,
    int* __restrict__ epos, int* __restrict__ cnt) {
  const int e = blockIdx.x;
  const int tid = threadIdx.x;
  const int lane = tid & 63;
  const int wave = tid >> 6;
  __shared__ int wsum[4];
  __shared__ int base_s;
  if (tid == 0) base_s = 0;
  __syncthreads();
  for (int t0 = 0; t0 < T_TOK; t0 += 256) {
    int t = t0 + tid;
    int i1 = tope[2 * t], i2 = tope[2 * t + 1];
    int slot = (i1 == e) ? 0 : ((i2 == e) ? 1 : -1);
    unsigned long long m = __ballot(slot >= 0);
    int wpre = __popcll(m & ((1ull << lane) - 1ull));
    if (lane == 0) wsum[wave] = __popcll(m);
    __syncthreads();                       // wsum ready; base_s stable
    int pre = wpre;
    for (int w = 0; w < wave; w++) pre += wsum[w];
    int total = wsum[0] + wsum[1] + wsum[2] + wsum[3];
    int b = base_s;
    if (slot >= 0) {
      int pos = b + pre;
      tok_list[e * T_TOK + pos] = t;
      epos[2 * t + slot] = (e << 16) | pos;
    }
    __syncthreads();                       // all done reading base_s/wsum
    if (tid == 0) base_s = b + total;
  }
  __syncthreads();
  if (tid == 0) cnt[e] = base_s;
}

__global__ void calc_off(const int* __restrict__ cnt, int* __restrict__ off) {
  if (threadIdx.x == 0) {
    int s = 0;
    for (int e = 0; e < E_NUM; e++) { off[e] = s; s += cnt[e]; }
  }
}

// ---------------------------------------------------------------------------
// GEMM1: 64x128 tile (M=64 tokens, N=128 cols of both g and u halves).
// 4 waves side by side in N (each 64x32 per matrix, acc 4x2). Two-barrier
// K-loop (proven R2 structure). ~164 regs/wave -> 3 waves/SIMD.
// ---------------------------------------------------------------------------
__global__ __launch_bounds__(256, 3) void gemm1_silu(
    const signed char* __restrict__ qw13, const signed char* __restrict__ qin,
    const float* __restrict__ s_in, const float* __restrict__ s13,
    const int* __restrict__ tok_list, const int* __restrict__ cnt,
    const int* __restrict__ off, float* __restrict__ act,
    unsigned int* __restrict__ amax) {
  const int e = blockIdx.z;
  const int ce = cnt[e];
  const int m0 = blockIdx.y * 64;
  if (m0 >= ce) return;
  const int n0 = blockIdx.x * 128;

  __shared__ __align__(16) signed char As[64 * 64];    // 4 KB
  __shared__ __align__(16) signed char Bg[128 * 64];   // 8 KB
  __shared__ __align__(16) signed char Bu[128 * 64];   // 8 KB

  const int tid = threadIdx.x;
  const int lane = tid & 63;
  const int wave = tid >> 6;
  const int quad = lane >> 4;
  const int ln = lane & 15;

  const int* tl = tok_list + e * T_TOK;
  const int rowA = tid >> 2;             // 0..63
  const int kc = (tid & 3) * 16;

  const int tA = tl[min(m0 + rowA, ce - 1)];
  const signed char* gA = qin + (size_t)tA * H_DIM + kc;
  const signed char* w13e = qw13 + (size_t)e * NI2 * H_DIM;
  const signed char* gBg0 = w13e + (size_t)(n0 + rowA) * H_DIM + kc;
  const signed char* gBg1 = w13e + (size_t)(n0 + rowA + 64) * H_DIM + kc;
  const signed char* gBu0 = gBg0 + (size_t)I_DIM * H_DIM;
  const signed char* gBu1 = gBg1 + (size_t)I_DIM * H_DIM;
  const int ldsA = tid * 16;             // natural row-major: (tid>>2)*64+(tid&3)*16
  const int lds1 = 4096 + ldsA;

  v4i accg[4][2], accu[4][2];
  v4i zero = {0, 0, 0, 0};
#pragma unroll
  for (int i = 0; i < 4; i++)
#pragma unroll
    for (int j = 0; j < 2; j++) { accg[i][j] = zero; accu[i][j] = zero; }

  for (int k0 = 0; k0 < H_DIM; k0 += 64) {
    __syncthreads();
    GLD_LDS16(gA + k0, As + ldsA);
    GLD_LDS16(gBg0 + k0, Bg + ldsA);
    GLD_LDS16(gBg1 + k0, Bg + lds1);
    GLD_LDS16(gBu0 + k0, Bu + ldsA);
    GLD_LDS16(gBu1 + k0, Bu + lds1);
    __syncthreads();

    v4i af[4], bgf[2], buf_[2];
#pragma unroll
    for (int mt = 0; mt < 4; mt++)
      af[mt] = *(const v4i*)(As + (mt * 16 + ln) * 64 + quad * 16);
#pragma unroll
    for (int nt = 0; nt < 2; nt++) {
      bgf[nt] = *(const v4i*)(Bg + (wave * 32 + nt * 16 + ln) * 64 + quad * 16);
      buf_[nt] = *(const v4i*)(Bu + (wave * 32 + nt * 16 + ln) * 64 + quad * 16);
    }
#pragma unroll
    for (int mt = 0; mt < 4; mt++)
#pragma unroll
      for (int nt = 0; nt < 2; nt++) {
        accg[mt][nt] = __builtin_amdgcn_mfma_i32_16x16x64_i8(af[mt], bgf[nt], accg[mt][nt], 0, 0, 0);
        accu[mt][nt] = __builtin_amdgcn_mfma_i32_16x16x64_i8(af[mt], buf_[nt], accu[mt][nt], 0, 0, 0);
      }
  }

  const float* s13e = s13 + e * NI2;
  float sg[2], su[2];
  int ncol[2];
#pragma unroll
  for (int nt = 0; nt < 2; nt++) {
    int n = n0 + wave * 32 + nt * 16 + ln;
    ncol[nt] = n;
    sg[nt] = s13e[n];
    su[nt] = s13e[I_DIM + n];
  }
  const int offe = off[e];
#pragma unroll
  for (int mt = 0; mt < 4; mt++) {
#pragma unroll
    for (int r = 0; r < 4; r++) {
      int mrel = m0 + mt * 16 + quad * 4 + r;
      bool valid = mrel < ce;
      int tok = tl[valid ? mrel : 0];
      float si = s_in[tok];
      int crow = offe + mrel;
      float* arow = act + (size_t)crow * I_DIM;
      float am = 0.f;
#pragma unroll
      for (int nt = 0; nt < 2; nt++) {
        float g = (float)accg[mt][nt][r] * si * sg[nt];
        float u = (float)accu[mt][nt][r] * si * su[nt];
        float a = g / (1.0f + expf(-g)) * u;
        if (valid) arow[ncol[nt]] = a;
        am = fmaxf(am, fabsf(a));
      }
      for (int s = 1; s < 16; s <<= 1) am = fmaxf(am, __shfl_xor(am, s, 16));
      if (valid && ln == 0) atomicMax(amax + crow, __float_as_uint(am));
    }
  }
}

// ---------------------------------------------------------------------------
// Per-row dynamic int8 quant of act
// ---------------------------------------------------------------------------
__global__ __launch_bounds__(256) void quant_act(const float* __restrict__ act,
                                                 const unsigned int* __restrict__ amax,
                                                 signed char* __restrict__ qa,
                                                 float* __restrict__ s_a) {
  const int r = blockIdx.x;
  float am = __uint_as_float(amax[r]);
  float s = fmaxf(am / 127.0f, 1e-8f);
  if (threadIdx.x == 0) s_a[r] = s;
  const float* arow = act + (size_t)r * I_DIM;
  signed char* qrow = qa + (size_t)r * I_DIM;
  for (int j = threadIdx.x; j < I_DIM; j += 256) {
    float q = rintf(arow[j] / s);
    q = fminf(127.f, fmaxf(-127.f, q));
    qrow[j] = (signed char)q;
  }
}

// ---------------------------------------------------------------------------
// GEMM2: 64x128 tile, h2s stores (no atomics)
// ---------------------------------------------------------------------------
__global__ __launch_bounds__(256, 4) void gemm2_h2(
    const signed char* __restrict__ qw2, const signed char* __restrict__ qa,
    const float* __restrict__ s_a, const float* __restrict__ s2w,
    const int* __restrict__ cnt, const int* __restrict__ off,
    float* __restrict__ h2s) {
  const int e = blockIdx.z;
  const int ce = cnt[e];
  const int m0 = blockIdx.y * 64;
  if (m0 >= ce) return;
  const int n0 = blockIdx.x * 128;
  const int offe = off[e];

  __shared__ __align__(16) signed char As[64 * 64];    // 4 KB
  __shared__ __align__(16) signed char Bs[128 * 64];   // 8 KB

  const int tid = threadIdx.x;
  const int lane = tid & 63;
  const int wave = tid >> 6;
  const int quad = lane >> 4;
  const int ln = lane & 15;

  const int rowA = tid >> 2;
  const int kc = (tid & 3) * 16;

  const signed char* gA = qa + (size_t)(offe + min(m0 + rowA, ce - 1)) * I_DIM + kc;
  const signed char* w2e = qw2 + (size_t)e * H_DIM * I_DIM;
  const signed char* gB0 = w2e + (size_t)(n0 + rowA) * I_DIM + kc;
  const signed char* gB1 = w2e + (size_t)(n0 + rowA + 64) * I_DIM + kc;
  const int ldsA = tid * 16;
  const int lds1 = 4096 + ldsA;

  v4i acc[4][2];
  v4i zero = {0, 0, 0, 0};
#pragma unroll
  for (int i = 0; i < 4; i++)
#pragma unroll
    for (int j = 0; j < 2; j++) acc[i][j] = zero;

  for (int k0 = 0; k0 < I_DIM; k0 += 64) {
    __syncthreads();
    GLD_LDS16(gA + k0, As + ldsA);
    GLD_LDS16(gB0 + k0, Bs + ldsA);
    GLD_LDS16(gB1 + k0, Bs + lds1);
    __syncthreads();

    v4i af[4], bf[2];
#pragma unroll
    for (int mt = 0; mt < 4; mt++)
      af[mt] = *(const v4i*)(As + (mt * 16 + ln) * 64 + quad * 16);
#pragma unroll
    for (int nt = 0; nt < 2; nt++)
      bf[nt] = *(const v4i*)(Bs + (wave * 32 + nt * 16 + ln) * 64 + quad * 16);
#pragma unroll
    for (int mt = 0; mt < 4; mt++)
#pragma unroll
      for (int nt = 0; nt < 2; nt++)
        acc[mt][nt] = __builtin_amdgcn_mfma_i32_16x16x64_i8(af[mt], bf[nt], acc[mt][nt], 0, 0, 0);
  }

  const float* s2e = s2w + e * H_DIM;
  float sw[2];
  int ncol[2];
#pragma unroll
  for (int nt = 0; nt < 2; nt++) {
    int n = n0 + wave * 32 + nt * 16 + ln;
    ncol[nt] = n;
    sw[nt] = s2e[n];
  }
#pragma unroll
  for (int mt = 0; mt < 4; mt++) {
#pragma unroll
    for (int r = 0; r < 4; r++) {
      int mrel = m0 + mt * 16 + quad * 4 + r;
      if (mrel >= ce) continue;
      float sa = s_a[offe + mrel];
      float* orow = h2s + (size_t)(offe + mrel) * H_DIM;
#pragma unroll
      for (int nt = 0; nt < 2; nt++)
        orow[ncol[nt]] = (float)acc[mt][nt][r] * sa * sw[nt];
    }
  }
}

// ---------------------------------------------------------------------------
// Final gather: out[t] = g1 * h2s[r1] + g2 * h2s[r2]
// ---------------------------------------------------------------------------
__global__ __launch_bounds__(256) void gather_out(
    const float* __restrict__ h2s, const int* __restrict__ epos,
    const float* __restrict__ gts, const int* __restrict__ off,
    float* __restrict__ out) {
  const int t = blockIdx.x;
  int a = epos[2 * t], b = epos[2 * t + 1];
  float g1 = gts[2 * t], g2 = gts[2 * t + 1];
  int r1 = off[a >> 16] + (a & 0xffff);
  int r2 = off[b >> 16] + (b & 0xffff);
  const float4* R1 = (const float4*)(h2s + (size_t)r1 * H_DIM);
  const float4* R2 = (const float4*)(h2s + (size_t)r2 * H_DIM);
  float4* O = (float4*)(out + (size_t)t * H_DIM);
  for (int c = threadIdx.x; c < H_DIM / 4; c += 256) {
    float4 x = R1[c], y = R2[c];
    float4 z;
    z.x = g1 * x.x + g2 * y.x;
    z.y = g1 * x.y + g2 * y.y;
    z.z = g1 * x.z + g2 * y.z;
    z.w = g1 * x.w + g2 * y.w;
    O[c] = z;
  }
}

// ---------------------------------------------------------------------------
extern "C" void kernel_launch(void* const* d_in, const int* in_sizes, int n_in,
                              void* d_out, int out_size, void* d_ws, size_t ws_size,
                              hipStream_t stream) {
  const float* hs = (const float*)d_in[0];
  const float* gw = (const float*)d_in[1];
  const int* w13 = (const int*)d_in[2];
  const float* s13 = (const float*)d_in[3];
  const int* w2 = (const int*)d_in[4];
  const float* s2w = (const float*)d_in[5];
  float* out = (float*)d_out;

  char* ws = (char*)d_ws;
  size_t o = 0;
  auto take = [&](size_t b) {
    char* p = ws + o;
    o += (b + 255) & ~(size_t)255;
    return p;
  };
  signed char* qw13 = (signed char*)take((size_t)E_NUM * NI2 * H_DIM);       // 46.1 MB
  signed char* qin = (signed char*)take((size_t)T_TOK * H_DIM);              // 8.4 MB
  float* act = (float*)take((size_t)T_TOK * 2 * I_DIM * 4);                  // 46.1 MB
  float* h2s = (float*)qw13;  // aliases dead qw13+qin+act space (67.1 MB needed)
  signed char* qw2 = (signed char*)take((size_t)E_NUM * H_DIM * I_DIM);      // 23.1 MB
  signed char* qa = (signed char*)take((size_t)T_TOK * 2 * I_DIM);           // 11.5 MB
  float* sin_ = (float*)take((size_t)T_TOK * 4);
  float* sa = (float*)take((size_t)T_TOK * 2 * 4);
  unsigned int* amax = (unsigned int*)take((size_t)T_TOK * 2 * 4);
  int* tokl = (int*)take((size_t)E_NUM * T_TOK * 4);
  int* tope = (int*)take((size_t)T_TOK * 2 * 4);
  int* epos = (int*)take((size_t)T_TOK * 2 * 4);
  float* gts = (float*)take((size_t)T_TOK * 2 * 4);
  int* cnt = (int*)take(E_NUM * 4);
  int* off = (int*)take(E_NUM * 4);

  hipMemsetAsync(amax, 0, (size_t)T_TOK * 2 * 4, stream);

  {
    int n16a = E_NUM * NI2 * H_DIM / 16;
    int n16b = E_NUM * H_DIM * I_DIM / 16;
    int n16tot = n16a + n16b;
    pack_all<<<(n16tot + 255) / 256, 256, 0, stream>>>(w13, w2, qw13, qw2, n16a, n16tot);
  }
  gate_route_quant<<<T_TOK, 256, 0, stream>>>(hs, gw, qin, sin_, tope, gts);
  build_lists<<<E_NUM, 256, 0, stream>>>(tope, tokl, epos, cnt);
  calc_off<<<1, 64, 0, stream>>>(cnt, off);
  {
    dim3 g(I_DIM / 128, T_TOK / 64, E_NUM);
    gemm1_silu<<<g, 256, 0, stream>>>(qw13, qin, sin_, s13, tokl, cnt, off, act, amax);
  }
  quant_act<<<T_TOK * 2, 256, 0, stream>>>(act, amax, qa, sa);
  {
    dim3 g(H_DIM / 128, T_TOK / 64, E_NUM);
    gemm2_h2<<<g, 256, 0, stream>>>(qw2, qa, sa, s2w, cnt, off, h2s);
  }
  gather_out<<<T_TOK, 256, 0, stream>>>(h2s, epos, gts, off, out);
}